// Round 2
// baseline (304.507 us; speedup 1.0000x reference)
//
#include <hip/hip_runtime.h>

typedef __attribute__((ext_vector_type(8))) __bf16 bf16x8;
typedef __attribute__((ext_vector_type(4))) float f32x4;
typedef __attribute__((ext_vector_type(8))) unsigned short u16x8;

#define MFMA(a, b, c) __builtin_amdgcn_mfma_f32_16x16x32_bf16((a), (b), (c), 0, 0, 0)
#define LOG2E 1.44269504088896340736f

__device__ __forceinline__ float b2f(unsigned short u) {
    union { unsigned int i; float f; } v; v.i = ((unsigned int)u) << 16; return v.f;
}
__device__ __forceinline__ unsigned short f2bf(float f) {
    union { float f; unsigned int i; } v; v.f = f;
    unsigned int u = v.i;
    return (unsigned short)((u + 0x7fffu + ((u >> 16) & 1u)) >> 16);
}

// async global->LDS, 16B per lane; LDS dest is wave-uniform base + lane*16 (m104),
// layouts below are arranged so lane order == contiguous LDS order.
__device__ __forceinline__ void gl_lds16(const void* g, void* l) {
    __builtin_amdgcn_global_load_lds(
        (const __attribute__((address_space(1))) void*)g,
        (__attribute__((address_space(3))) void*)l,
        16, 0, 0);
}

// ---------------- fp32 -> bf16 conversion of all 5 inputs (one launch) ------------
// x: 4M elems, each w: 1M elems. 8 elems/thread -> 1M threads.
__global__ __launch_bounds__(256) void cvt_all(const float* __restrict__ x,
                                               const float* __restrict__ wq,
                                               const float* __restrict__ wk,
                                               const float* __restrict__ wv,
                                               const float* __restrict__ wo,
                                               unsigned short* __restrict__ xb,
                                               unsigned short* __restrict__ wqb,
                                               unsigned short* __restrict__ wkb,
                                               unsigned short* __restrict__ wvb,
                                               unsigned short* __restrict__ wob) {
    int id = blockIdx.x * 256 + threadIdx.x;  // [0, 1M)
    const float* src; unsigned short* dst; size_t off;
    if (id < 524288)      { src = x;  dst = xb;  off = (size_t)id * 8; }
    else if (id < 655360) { src = wq; dst = wqb; off = (size_t)(id - 524288) * 8; }
    else if (id < 786432) { src = wk; dst = wkb; off = (size_t)(id - 655360) * 8; }
    else if (id < 917504) { src = wv; dst = wvb; off = (size_t)(id - 786432) * 8; }
    else                  { src = wo; dst = wob; off = (size_t)(id - 917504) * 8; }
    float4 a = *(const float4*)(src + off);
    float4 b = *(const float4*)(src + off + 4);
    u16x8 o;
    o[0] = f2bf(a.x); o[1] = f2bf(a.y); o[2] = f2bf(a.z); o[3] = f2bf(a.w);
    o[4] = f2bf(b.x); o[5] = f2bf(b.y); o[6] = f2bf(b.z); o[7] = f2bf(b.w);
    *(u16x8*)(dst + off) = o;
}

// ---------------- GEMM: C[MxN] = A[MxK] * B[NxK]^T, bf16 in, fp32 accum ----------
// K=1024, ldc=1024. 128x128 tile, BK=32, 4 waves, each 2x2 grid of 4x4 MFMA tiles.
template <typename OutT>
__device__ __forceinline__ void gemm128_bt(const unsigned short* __restrict__ A,
                                           const unsigned short* __restrict__ B,
                                           OutT* __restrict__ C,
                                           int m0, int n0,
                                           unsigned short* As, unsigned short* Bs) {
    const int tid = threadIdx.x;
    const int w = tid >> 6, lane = tid & 63;
    const int quad = lane >> 4, l15 = lane & 15;
    const int wm = w & 1, wn = w >> 1;

    f32x4 acc[4][4];
#pragma unroll
    for (int mt = 0; mt < 4; ++mt)
#pragma unroll
        for (int nt = 0; nt < 4; ++nt) acc[mt][nt] = f32x4{0.f, 0.f, 0.f, 0.f};

    for (int k0 = 0; k0 < 1024; k0 += 32) {
        __syncthreads();
#pragma unroll
        for (int i = 0; i < 2; ++i) {
            int seg = w * 2 + i;
            int r = seg * 16 + (lane >> 2);
            int cs = (lane & 3) * 8;
            gl_lds16(A + (size_t)(m0 + r) * 1024 + k0 + cs, As + r * 32 + cs);
            gl_lds16(B + (size_t)(n0 + r) * 1024 + k0 + cs, Bs + r * 32 + cs);
        }
        __syncthreads();  // compiler emits s_waitcnt vmcnt(0) before s_barrier

        bf16x8 af[4], bfr[4];
#pragma unroll
        for (int mt = 0; mt < 4; ++mt)
            af[mt] = *(const bf16x8*)(As + (wm * 64 + mt * 16 + l15) * 32 + quad * 8);
#pragma unroll
        for (int nt = 0; nt < 4; ++nt)
            bfr[nt] = *(const bf16x8*)(Bs + (wn * 64 + nt * 16 + l15) * 32 + quad * 8);
#pragma unroll
        for (int mt = 0; mt < 4; ++mt)
#pragma unroll
            for (int nt = 0; nt < 4; ++nt)
                acc[mt][nt] = MFMA(af[mt], bfr[nt], acc[mt][nt]);
    }

#pragma unroll
    for (int mt = 0; mt < 4; ++mt) {
        int grow = m0 + wm * 64 + mt * 16 + quad * 4;
#pragma unroll
        for (int nt = 0; nt < 4; ++nt) {
            int gcol = n0 + wn * 64 + nt * 16 + l15;
#pragma unroll
            for (int r = 0; r < 4; ++r) {
                float val = acc[mt][nt][r];
                if constexpr (sizeof(OutT) == 2)
                    C[(size_t)(grow + r) * 1024 + gcol] = (OutT)f2bf(val);
                else
                    C[(size_t)(grow + r) * 1024 + gcol] = (OutT)val;
            }
        }
    }
}

__global__ __launch_bounds__(256) void gemm_qkv(const unsigned short* __restrict__ X,
                                                const unsigned short* __restrict__ Wq,
                                                const unsigned short* __restrict__ Wk,
                                                const unsigned short* __restrict__ Wv,
                                                unsigned short* __restrict__ Qo,
                                                unsigned short* __restrict__ Ko,
                                                unsigned short* __restrict__ Vo) {
    __shared__ unsigned short As[128 * 32];
    __shared__ unsigned short Bs[128 * 32];
    int m0 = blockIdx.x * 128;
    int sel = blockIdx.y >> 3;
    int n0 = (blockIdx.y & 7) * 128;
    const unsigned short* B = (sel == 0) ? Wq : ((sel == 1) ? Wk : Wv);
    unsigned short* C = (sel == 0) ? Qo : ((sel == 1) ? Ko : Vo);
    gemm128_bt<unsigned short>(X, B, C, m0, n0, As, Bs);
}

__global__ __launch_bounds__(256) void gemm_out(const unsigned short* __restrict__ A,
                                                const unsigned short* __restrict__ Wo,
                                                float* __restrict__ C) {
    __shared__ unsigned short As[128 * 32];
    __shared__ unsigned short Bs[128 * 32];
    gemm128_bt<float>(A, Wo, C, blockIdx.x * 128, blockIdx.y * 128, As, Bs);
}

// ---------------- RoPE on Q and K in-place; folds 1/sqrt(d_k)=0.125 into Q --------
__global__ __launch_bounds__(256) void rope_qk(unsigned short* __restrict__ Q,
                                               unsigned short* __restrict__ K) {
    int id = blockIdx.x * 256 + threadIdx.x;   // 0 .. 2*4096*512-1
    int tsel = id >> 21;
    int rgt = id & 0x1FFFFF;
    int row = rgt >> 9;        // token row 0..4095
    int p = rgt & 511;         // pair within row
    int pp = p & 31;           // pair within head
    int col = (p >> 5) * 64 + pp * 2;
    float pos = (float)(row & 2047);
    // inv_freq = 10000^(-2*pp/64) = exp2(-pp * log2(10000)/32)
    float inv_freq = exp2f(-0.41524101186092029f * (float)pp);
    float ang = pos * inv_freq;
    float sn, cs;
    sincosf(ang, &sn, &cs);
    unsigned short* buf = tsel ? K : Q;
    float scale = tsel ? 1.0f : 0.125f;
    size_t base = (size_t)row * 1024 + col;
    float xe = b2f(buf[base]), xo = b2f(buf[base + 1]);
    buf[base]     = f2bf((xe * cs - xo * sn) * scale);
    buf[base + 1] = f2bf((xe * sn + xo * cs) * scale);
}

// ---------------- V transpose: [b*2048+s][h*64+d] -> Vt[bh][d][s] ------------------
__global__ __launch_bounds__(256) void transpose_v(const unsigned short* __restrict__ V,
                                                   unsigned short* __restrict__ Vt) {
    int st = blockIdx.x, bh = blockIdx.y;
    int b = bh >> 4, h = bh & 15;
    __shared__ unsigned short t[64][72];  // +8 pad breaks bank conflicts
    int tid = threadIdx.x;
#pragma unroll
    for (int it = 0; it < 2; ++it) {
        int idx = it * 256 + tid;
        int sl = idx >> 3, dg = (idx & 7) * 8;
        u16x8 val = *(const u16x8*)(V + (size_t)(b * 2048 + st * 64 + sl) * 1024 + h * 64 + dg);
#pragma unroll
        for (int j = 0; j < 8; ++j) t[sl][dg + j] = val[j];
    }
    __syncthreads();
#pragma unroll
    for (int it = 0; it < 2; ++it) {
        int idx = it * 256 + tid;
        int dl = idx >> 3, sg = (idx & 7) * 8;
        u16x8 v;
#pragma unroll
        for (int j = 0; j < 8; ++j) v[j] = t[sg + j][dl];
        *(u16x8*)(Vt + (size_t)(bh * 64 + dl) * 2048 + st * 64 + sg) = v;
    }
}

// ---------------- Flash attention (causal, online softmax) ------------------------
// grid (32 q-tiles, 32 bh); block 256 = 4 waves; wave owns 16 q-rows; key blocks of 64.
__global__ __launch_bounds__(256) void flash_attn(const unsigned short* __restrict__ Q,
                                                  const unsigned short* __restrict__ Kb,
                                                  const unsigned short* __restrict__ Vt,
                                                  unsigned short* __restrict__ O) {
    int qt = 31 - blockIdx.x;  // largest tiles first (load balance)
    int bh = blockIdx.y;
    int b = bh >> 4, h = bh & 15;
    int tid = threadIdx.x, w = tid >> 6, lane = tid & 63;
    int quad = lane >> 4, l15 = lane & 15;
    int qrow0 = b * 2048 + qt * 64 + w * 16;  // global token row base for this wave
    int qpos0 = qt * 64 + w * 16;             // sequence position base

    __shared__ unsigned short Ks[64 * 64];     // [key][d]
    __shared__ unsigned short Vs[64 * 64];     // [d][key]  (from Vt)
    __shared__ unsigned short Ps[4][16 * 64];  // per-wave P scratch [qrow][key]

    bf16x8 qf0, qf1;
    {
        const unsigned short* qp = Q + (size_t)(qrow0 + l15) * 1024 + h * 64 + quad * 8;
        qf0 = *(const bf16x8*)qp;
        qf1 = *(const bf16x8*)(qp + 32);
    }

    f32x4 accO[4];
#pragma unroll
    for (int nt = 0; nt < 4; ++nt) accO[nt] = f32x4{0.f, 0.f, 0.f, 0.f};
    float m_r[4], l_r[4];
#pragma unroll
    for (int r = 0; r < 4; ++r) { m_r[r] = -1e30f; l_r[r] = 0.f; }

    int nkb = qt + 1;
    for (int kb = 0; kb < nkb; ++kb) {
        __syncthreads();  // previous compute done before restage
#pragma unroll
        for (int i = 0; i < 2; ++i) {
            int seg = w * 2 + i;
            int rr = seg * 8 + (lane >> 3);
            int cs = (lane & 7) * 8;
            gl_lds16(Kb + (size_t)(b * 2048 + kb * 64 + rr) * 1024 + h * 64 + cs,
                     Ks + rr * 64 + cs);
            gl_lds16(Vt + (size_t)(bh * 64 + rr) * 2048 + kb * 64 + cs,
                     Vs + rr * 64 + cs);
        }
        __syncthreads();

        if (kb * 64 <= qpos0 + 15) {  // wave-uniform skip of fully-masked key blocks
            // ---- S = Q K^T (scale pre-folded into Q) ----
            f32x4 s[4];
#pragma unroll
            for (int nt = 0; nt < 4; ++nt) {
                bf16x8 kf0 = *(const bf16x8*)(Ks + (nt * 16 + l15) * 64 + quad * 8);
                bf16x8 kf1 = *(const bf16x8*)(Ks + (nt * 16 + l15) * 64 + 32 + quad * 8);
                f32x4 z = f32x4{0.f, 0.f, 0.f, 0.f};
                s[nt] = MFMA(qf0, kf0, z);
                s[nt] = MFMA(qf1, kf1, s[nt]);
            }
            // ---- causal mask + row max ----
            float tmax[4] = {-1e30f, -1e30f, -1e30f, -1e30f};
#pragma unroll
            for (int nt = 0; nt < 4; ++nt) {
                int kpos = kb * 64 + nt * 16 + l15;
#pragma unroll
                for (int r = 0; r < 4; ++r) {
                    int qpos = qpos0 + quad * 4 + r;
                    if (kpos > qpos) s[nt][r] = -1e30f;
                    tmax[r] = fmaxf(tmax[r], s[nt][r]);
                }
            }
#pragma unroll
            for (int off = 1; off < 16; off <<= 1)
#pragma unroll
                for (int r = 0; r < 4; ++r)
                    tmax[r] = fmaxf(tmax[r], __shfl_xor(tmax[r], off));
            // ---- online softmax update ----
            float alpha[4];
#pragma unroll
            for (int r = 0; r < 4; ++r) {
                float mn = fmaxf(m_r[r], tmax[r]);
                alpha[r] = exp2f((m_r[r] - mn) * LOG2E);
                m_r[r] = mn;
            }
            float rsum[4] = {0.f, 0.f, 0.f, 0.f};
#pragma unroll
            for (int nt = 0; nt < 4; ++nt)
#pragma unroll
                for (int r = 0; r < 4; ++r) {
                    float p = exp2f((s[nt][r] - m_r[r]) * LOG2E);
                    s[nt][r] = p;
                    rsum[r] += p;
                }
#pragma unroll
            for (int off = 1; off < 16; off <<= 1)
#pragma unroll
                for (int r = 0; r < 4; ++r) rsum[r] += __shfl_xor(rsum[r], off);
#pragma unroll
            for (int r = 0; r < 4; ++r) l_r[r] = l_r[r] * alpha[r] + rsum[r];
#pragma unroll
            for (int nt = 0; nt < 4; ++nt)
#pragma unroll
                for (int r = 0; r < 4; ++r) accO[nt][r] *= alpha[r];
            // ---- P: C-layout -> LDS -> A-layout (bf16) ----
            unsigned short* Pw = Ps[w];
#pragma unroll
            for (int nt = 0; nt < 4; ++nt)
#pragma unroll
                for (int r = 0; r < 4; ++r)
                    Pw[(quad * 4 + r) * 64 + nt * 16 + l15] = f2bf(s[nt][r]);
            __asm__ volatile("s_waitcnt lgkmcnt(0)" ::: "memory");  // wave-local LDS RAW
            bf16x8 pf0 = *(const bf16x8*)(Pw + l15 * 64 + quad * 8);
            bf16x8 pf1 = *(const bf16x8*)(Pw + l15 * 64 + 32 + quad * 8);
            // ---- O += P V ----
#pragma unroll
            for (int nt = 0; nt < 4; ++nt) {
                bf16x8 vf0 = *(const bf16x8*)(Vs + (nt * 16 + l15) * 64 + quad * 8);
                bf16x8 vf1 = *(const bf16x8*)(Vs + (nt * 16 + l15) * 64 + 32 + quad * 8);
                accO[nt] = MFMA(pf0, vf0, accO[nt]);
                accO[nt] = MFMA(pf1, vf1, accO[nt]);
            }
        }
    }
    // ---- epilogue: O / l ----
    float inv[4];
#pragma unroll
    for (int r = 0; r < 4; ++r) inv[r] = 1.0f / l_r[r];
#pragma unroll
    for (int nt = 0; nt < 4; ++nt)
#pragma unroll
        for (int r = 0; r < 4; ++r)
            O[(size_t)(qrow0 + quad * 4 + r) * 1024 + h * 64 + nt * 16 + l15] =
                f2bf(accO[nt][r] * inv[r]);
}

extern "C" void kernel_launch(void* const* d_in, const int* in_sizes, int n_in,
                              void* d_out, int out_size, void* d_ws, size_t ws_size,
                              hipStream_t stream) {
    (void)in_sizes; (void)n_in; (void)out_size; (void)ws_size;
    const float* x  = (const float*)d_in[0];
    const float* wq = (const float*)d_in[1];
    const float* wk = (const float*)d_in[2];
    const float* wv = (const float*)d_in[3];
    const float* wo = (const float*)d_in[4];
    float* out = (float*)d_out;

    const size_t T = (size_t)4096 * 1024;  // activation tensor elems (8 MB bf16)
    const size_t W = (size_t)1024 * 1024;  // weight tensor elems (2 MB bf16)
    unsigned short* Q   = (unsigned short*)d_ws;
    unsigned short* K   = Q + T;
    unsigned short* Vt  = K + T;
    unsigned short* Vr  = Vt + T;
    unsigned short* AO  = Vr + T;
    unsigned short* xb  = AO + T;
    unsigned short* wqb = xb + T;
    unsigned short* wkb = wqb + W;
    unsigned short* wvb = wkb + W;
    unsigned short* wob = wvb + W;
    // total ws use: 6*8MB + 4*2MB = 56 MB

    cvt_all    <<<dim3(4096),   256, 0, stream>>>(x, wq, wk, wv, wo, xb, wqb, wkb, wvb, wob);
    gemm_qkv   <<<dim3(32, 24), 256, 0, stream>>>(xb, wqb, wkb, wvb, Q, K, Vr);
    rope_qk    <<<dim3(16384),  256, 0, stream>>>(Q, K);
    transpose_v<<<dim3(32, 32), 256, 0, stream>>>(Vr, Vt);
    flash_attn <<<dim3(32, 32), 256, 0, stream>>>(Q, K, Vt, AO);
    gemm_out   <<<dim3(32, 8),  256, 0, stream>>>(AO, wob, out);
}

// Round 3
// 229.346 us; speedup vs baseline: 1.3277x; 1.3277x over previous
//
#include <hip/hip_runtime.h>

typedef __attribute__((ext_vector_type(8))) __bf16 bf16x8;
typedef __attribute__((ext_vector_type(4))) float f32x4;
typedef __attribute__((ext_vector_type(8))) unsigned short u16x8;

#define MFMA(a, b, c) __builtin_amdgcn_mfma_f32_16x16x32_bf16((a), (b), (c), 0, 0, 0)
#define LOG2E 1.44269504088896340736f

__device__ __forceinline__ float b2f(unsigned short u) {
    union { unsigned int i; float f; } v; v.i = ((unsigned int)u) << 16; return v.f;
}
__device__ __forceinline__ unsigned short f2bf(float f) {
    union { float f; unsigned int i; } v; v.f = f;
    unsigned int u = v.i;
    return (unsigned short)((u + 0x7fffu + ((u >> 16) & 1u)) >> 16);
}

// async global->LDS, 16B/lane. HW dest = wave-uniform base + lane*16 (m104).
// Swizzling is done on the GLOBAL side: lane i fetches the chunk that belongs
// at LDS position i, so bank-conflict-free layouts coexist with gl_lds16.
__device__ __forceinline__ void gl_lds16(const void* g, void* l) {
    __builtin_amdgcn_global_load_lds(
        (const __attribute__((address_space(1))) void*)g,
        (__attribute__((address_space(3))) void*)l,
        16, 0, 0);
}

// ---------------- fp32 -> bf16 conversion of all 5 inputs (one launch) ------------
__global__ __launch_bounds__(256) void cvt_all(const float* __restrict__ x,
                                               const float* __restrict__ wq,
                                               const float* __restrict__ wk,
                                               const float* __restrict__ wv,
                                               const float* __restrict__ wo,
                                               unsigned short* __restrict__ xb,
                                               unsigned short* __restrict__ wqb,
                                               unsigned short* __restrict__ wkb,
                                               unsigned short* __restrict__ wvb,
                                               unsigned short* __restrict__ wob) {
    int id = blockIdx.x * 256 + threadIdx.x;  // [0, 1M)
    const float* src; unsigned short* dst; size_t off;
    if (id < 524288)      { src = x;  dst = xb;  off = (size_t)id * 8; }
    else if (id < 655360) { src = wq; dst = wqb; off = (size_t)(id - 524288) * 8; }
    else if (id < 786432) { src = wk; dst = wkb; off = (size_t)(id - 655360) * 8; }
    else if (id < 917504) { src = wv; dst = wvb; off = (size_t)(id - 786432) * 8; }
    else                  { src = wo; dst = wob; off = (size_t)(id - 917504) * 8; }
    float4 a = *(const float4*)(src + off);
    float4 b = *(const float4*)(src + off + 4);
    u16x8 o;
    o[0] = f2bf(a.x); o[1] = f2bf(a.y); o[2] = f2bf(a.z); o[3] = f2bf(a.w);
    o[4] = f2bf(b.x); o[5] = f2bf(b.y); o[6] = f2bf(b.z); o[7] = f2bf(b.w);
    *(u16x8*)(dst + off) = o;
}

// ---------------- GEMM: C[MxN] = A[MxK]*B[NxK]^T, bf16 in, fp32 accum -------------
// 128x128 tile, BK=32 (row=64B=4 chunks). LDS chunk (r,cpos) holds source chunk
// cpos^((r>>1)&3) -> frag ds_read_b128 is 2-way (free) instead of 8-way.
template <typename OutT>
__device__ __forceinline__ void gemm128_bt(const unsigned short* __restrict__ A,
                                           const unsigned short* __restrict__ B,
                                           OutT* __restrict__ C,
                                           int m0, int n0,
                                           unsigned short* As, unsigned short* Bs) {
    const int tid = threadIdx.x;
    const int w = tid >> 6, lane = tid & 63;
    const int quad = lane >> 4, l15 = lane & 15;
    const int wm = w & 1, wn = w >> 1;

    f32x4 acc[4][4];
#pragma unroll
    for (int mt = 0; mt < 4; ++mt)
#pragma unroll
        for (int nt = 0; nt < 4; ++nt) acc[mt][nt] = f32x4{0.f, 0.f, 0.f, 0.f};

    for (int k0 = 0; k0 < 1024; k0 += 32) {
        __syncthreads();
#pragma unroll
        for (int i = 0; i < 2; ++i) {
            int L = (w * 2 + i) * 64 + lane;      // chunk index in tile
            int r = L >> 2;
            int c = (L & 3) ^ ((r >> 1) & 3);     // swizzled source chunk
            gl_lds16(A + (size_t)(m0 + r) * 1024 + k0 + c * 8, As + L * 8);
            gl_lds16(B + (size_t)(n0 + r) * 1024 + k0 + c * 8, Bs + L * 8);
        }
        __syncthreads();

        bf16x8 af[4], bfr[4];
#pragma unroll
        for (int mt = 0; mt < 4; ++mt) {
            int row = wm * 64 + mt * 16 + l15;
            af[mt] = *(const bf16x8*)(As + row * 32 + (quad ^ ((row >> 1) & 3)) * 8);
        }
#pragma unroll
        for (int nt = 0; nt < 4; ++nt) {
            int row = wn * 64 + nt * 16 + l15;
            bfr[nt] = *(const bf16x8*)(Bs + row * 32 + (quad ^ ((row >> 1) & 3)) * 8);
        }
#pragma unroll
        for (int mt = 0; mt < 4; ++mt)
#pragma unroll
            for (int nt = 0; nt < 4; ++nt)
                acc[mt][nt] = MFMA(af[mt], bfr[nt], acc[mt][nt]);
    }

#pragma unroll
    for (int mt = 0; mt < 4; ++mt) {
        int grow = m0 + wm * 64 + mt * 16 + quad * 4;
#pragma unroll
        for (int nt = 0; nt < 4; ++nt) {
            int gcol = n0 + wn * 64 + nt * 16 + l15;
#pragma unroll
            for (int r = 0; r < 4; ++r) {
                float val = acc[mt][nt][r];
                if constexpr (sizeof(OutT) == 2)
                    C[(size_t)(grow + r) * 1024 + gcol] = (OutT)f2bf(val);
                else
                    C[(size_t)(grow + r) * 1024 + gcol] = (OutT)val;
            }
        }
    }
}

__global__ __launch_bounds__(256) void gemm_qkv(const unsigned short* __restrict__ X,
                                                const unsigned short* __restrict__ Wq,
                                                const unsigned short* __restrict__ Wk,
                                                const unsigned short* __restrict__ Wv,
                                                unsigned short* __restrict__ Qo,
                                                unsigned short* __restrict__ Ko,
                                                unsigned short* __restrict__ Vo) {
    __shared__ unsigned short As[128 * 32];
    __shared__ unsigned short Bs[128 * 32];
    int m0 = blockIdx.x * 128;
    int sel = blockIdx.y >> 3;
    int n0 = (blockIdx.y & 7) * 128;
    const unsigned short* B = (sel == 0) ? Wq : ((sel == 1) ? Wk : Wv);
    unsigned short* C = (sel == 0) ? Qo : ((sel == 1) ? Ko : Vo);
    gemm128_bt<unsigned short>(X, B, C, m0, n0, As, Bs);
}

__global__ __launch_bounds__(256) void gemm_out(const unsigned short* __restrict__ A,
                                                const unsigned short* __restrict__ Wo,
                                                float* __restrict__ C) {
    __shared__ unsigned short As[128 * 32];
    __shared__ unsigned short Bs[128 * 32];
    gemm128_bt<float>(A, Wo, C, blockIdx.x * 128, blockIdx.y * 128, As, Bs);
}

// ---------------- RoPE in-place; Q gets 0.125*log2(e) folded in (M=0 softmax) -----
__global__ __launch_bounds__(256) void rope_qk(unsigned short* __restrict__ Q,
                                               unsigned short* __restrict__ K) {
    int id = blockIdx.x * 256 + threadIdx.x;   // 0 .. 2*4096*512-1
    int tsel = id >> 21;
    int rgt = id & 0x1FFFFF;
    int row = rgt >> 9;
    int p = rgt & 511;
    int pp = p & 31;
    int col = (p >> 5) * 64 + pp * 2;
    float pos = (float)(row & 2047);
    float inv_freq = exp2f(-0.41524101186092029f * (float)pp);
    float ang = pos * inv_freq;
    float sn, cs;
    sincosf(ang, &sn, &cs);
    unsigned short* buf = tsel ? K : Q;
    float scale = tsel ? 1.0f : (0.125f * LOG2E);
    size_t base = (size_t)row * 1024 + col;
    float xe = b2f(buf[base]), xo = b2f(buf[base + 1]);
    buf[base]     = f2bf((xe * cs - xo * sn) * scale);
    buf[base + 1] = f2bf((xe * sn + xo * cs) * scale);
}

// ---------------- V transpose: [b*2048+s][h*64+d] -> Vt[bh][d][s] ------------------
__global__ __launch_bounds__(256) void transpose_v(const unsigned short* __restrict__ V,
                                                   unsigned short* __restrict__ Vt) {
    int st = blockIdx.x, bh = blockIdx.y;
    int b = bh >> 4, h = bh & 15;
    __shared__ unsigned short t[64][72];
    int tid = threadIdx.x;
#pragma unroll
    for (int it = 0; it < 2; ++it) {
        int idx = it * 256 + tid;
        int sl = idx >> 3, dg = (idx & 7) * 8;
        u16x8 val = *(const u16x8*)(V + (size_t)(b * 2048 + st * 64 + sl) * 1024 + h * 64 + dg);
#pragma unroll
        for (int j = 0; j < 8; ++j) t[sl][dg + j] = val[j];
    }
    __syncthreads();
#pragma unroll
    for (int it = 0; it < 2; ++it) {
        int idx = it * 256 + tid;
        int dl = idx >> 3, sg = (idx & 7) * 8;
        u16x8 v;
#pragma unroll
        for (int j = 0; j < 8; ++j) v[j] = t[sg + j][dl];
        *(u16x8*)(Vt + (size_t)(bh * 64 + dl) * 2048 + st * 64 + sg) = v;
    }
}

// ---------------- Flash attention, causal, M=0 (no online max) ---------------------
// grid (32 q-tiles largest-first, 32 bh); 4 waves; wave owns 16 q-rows; key blocks 64.
// Numerator accO and denominator lsum accumulate unnormalized exp(s) in fp32.
// K/V staged with XOR(r&7) chunk swizzle -> all ds_read_b128 are 2-way (free).
__global__ __launch_bounds__(256) void flash_attn(const unsigned short* __restrict__ Q,
                                                  const unsigned short* __restrict__ Kb,
                                                  const unsigned short* __restrict__ Vt,
                                                  unsigned short* __restrict__ O) {
    int qt = 31 - blockIdx.x;
    int bh = blockIdx.y;
    int b = bh >> 4, h = bh & 15;
    int tid = threadIdx.x, w = tid >> 6, lane = tid & 63;
    int quad = lane >> 4, l15 = lane & 15;
    int qrow0 = b * 2048 + qt * 64 + w * 16;
    int qpos0 = qt * 64 + w * 16;

    __shared__ unsigned short Ks[64 * 64];     // [key][d], chunk-swizzled
    __shared__ unsigned short Vs[64 * 64];     // [d][key], chunk-swizzled
    __shared__ unsigned short Ps[4][16 * 72];  // per-wave P scratch, stride 72 (2-way)

    bf16x8 qf0, qf1;
    {
        const unsigned short* qp = Q + (size_t)(qrow0 + l15) * 1024 + h * 64 + quad * 8;
        qf0 = *(const bf16x8*)qp;
        qf1 = *(const bf16x8*)(qp + 32);
    }

    // staging: chunk L=(w*2+i)*64+lane; row r=L>>3, lds col cpos=L&7 holds src chunk cpos^(r&7)
    int L0 = w * 128 + lane;       // i=0
    int L1 = L0 + 64;              // i=1
    int r0 = L0 >> 3, c0s = (L0 & 7) ^ (r0 & 7);
    int r1 = L1 >> 3, c1s = (L1 & 7) ^ (r1 & 7);
    const unsigned short* Kg0 = Kb + (size_t)(b * 2048 + r0) * 1024 + h * 64 + c0s * 8;
    const unsigned short* Kg1 = Kb + (size_t)(b * 2048 + r1) * 1024 + h * 64 + c1s * 8;
    const unsigned short* Vg0 = Vt + (size_t)(bh * 64 + r0) * 2048 + c0s * 8;
    const unsigned short* Vg1 = Vt + (size_t)(bh * 64 + r1) * 2048 + c1s * 8;

    f32x4 accO[4];
#pragma unroll
    for (int nt = 0; nt < 4; ++nt) accO[nt] = f32x4{0.f, 0.f, 0.f, 0.f};
    float lsum[4] = {0.f, 0.f, 0.f, 0.f};

    int nkb = qt + 1;
    for (int kb = 0; kb < nkb; ++kb) {
        __syncthreads();
        {
            size_t ko = (size_t)kb * 64 * 1024;  // 64 token rows
            size_t vo = (size_t)kb * 64;         // 64 key columns
            gl_lds16(Kg0 + ko, Ks + L0 * 8);
            gl_lds16(Kg1 + ko, Ks + L1 * 8);
            gl_lds16(Vg0 + vo, Vs + L0 * 8);
            gl_lds16(Vg1 + vo, Vs + L1 * 8);
        }
        __syncthreads();

        if (kb * 64 <= qpos0 + 15) {   // wave-uniform skip of fully-masked blocks
            // ---- S' = (QK^T) * 0.125*log2e (folded into Q) ----
            f32x4 s[4];
#pragma unroll
            for (int nt = 0; nt < 4; ++nt) {
                int row = nt * 16 + l15;
                int cof = (quad ^ (row & 7)) * 8;
                bf16x8 kf0 = *(const bf16x8*)(Ks + row * 64 + cof);
                bf16x8 kf1 = *(const bf16x8*)(Ks + row * 64 + (cof ^ 32));
                f32x4 z = f32x4{0.f, 0.f, 0.f, 0.f};
                s[nt] = MFMA(qf0, kf0, z);
                s[nt] = MFMA(qf1, kf1, s[nt]);
            }
            // ---- P = exp2(s'), mask, accumulate denominator, store bf16 P ----
            unsigned short* Pw = Ps[w];
#pragma unroll
            for (int nt = 0; nt < 4; ++nt) {
                int kpos = kb * 64 + nt * 16 + l15;
#pragma unroll
                for (int r = 0; r < 4; ++r) {
                    int qpos = qpos0 + quad * 4 + r;
                    float e = exp2f(s[nt][r]);
                    e = (kpos > qpos) ? 0.f : e;
                    lsum[r] += e;
                    Pw[(quad * 4 + r) * 72 + nt * 16 + l15] = f2bf(e);
                }
            }
            __asm__ volatile("s_waitcnt lgkmcnt(0)" ::: "memory");  // wave-local LDS RAW
            bf16x8 pf0 = *(const bf16x8*)(Pw + l15 * 72 + quad * 8);
            bf16x8 pf1 = *(const bf16x8*)(Pw + l15 * 72 + 32 + quad * 8);
            // ---- O += P V ----
#pragma unroll
            for (int nt = 0; nt < 4; ++nt) {
                int row = nt * 16 + l15;
                int cof = (quad ^ (row & 7)) * 8;
                bf16x8 vf0 = *(const bf16x8*)(Vs + row * 64 + cof);
                bf16x8 vf1 = *(const bf16x8*)(Vs + row * 64 + (cof ^ 32));
                accO[nt] = MFMA(pf0, vf0, accO[nt]);
                accO[nt] = MFMA(pf1, vf1, accO[nt]);
            }
        }
    }
    // ---- epilogue: reduce denominator across the 16 lanes of each quad ----
#pragma unroll
    for (int off = 1; off < 16; off <<= 1)
#pragma unroll
        for (int r = 0; r < 4; ++r) lsum[r] += __shfl_xor(lsum[r], off);
    float inv[4];
#pragma unroll
    for (int r = 0; r < 4; ++r) inv[r] = 1.0f / lsum[r];
#pragma unroll
    for (int nt = 0; nt < 4; ++nt)
#pragma unroll
        for (int r = 0; r < 4; ++r)
            O[(size_t)(qrow0 + quad * 4 + r) * 1024 + h * 64 + nt * 16 + l15] =
                f2bf(accO[nt][r] * inv[r]);
}

extern "C" void kernel_launch(void* const* d_in, const int* in_sizes, int n_in,
                              void* d_out, int out_size, void* d_ws, size_t ws_size,
                              hipStream_t stream) {
    (void)in_sizes; (void)n_in; (void)out_size; (void)ws_size;
    const float* x  = (const float*)d_in[0];
    const float* wq = (const float*)d_in[1];
    const float* wk = (const float*)d_in[2];
    const float* wv = (const float*)d_in[3];
    const float* wo = (const float*)d_in[4];
    float* out = (float*)d_out;

    const size_t T = (size_t)4096 * 1024;
    const size_t W = (size_t)1024 * 1024;
    unsigned short* Q   = (unsigned short*)d_ws;
    unsigned short* K   = Q + T;
    unsigned short* Vt  = K + T;
    unsigned short* Vr  = Vt + T;
    unsigned short* AO  = Vr + T;
    unsigned short* xb  = AO + T;
    unsigned short* wqb = xb + T;
    unsigned short* wkb = wqb + W;
    unsigned short* wvb = wkb + W;
    unsigned short* wob = wvb + W;

    cvt_all    <<<dim3(4096),   256, 0, stream>>>(x, wq, wk, wv, wo, xb, wqb, wkb, wvb, wob);
    gemm_qkv   <<<dim3(32, 24), 256, 0, stream>>>(xb, wqb, wkb, wvb, Q, K, Vr);
    rope_qk    <<<dim3(16384),  256, 0, stream>>>(Q, K);
    transpose_v<<<dim3(32, 32), 256, 0, stream>>>(Vr, Vt);
    flash_attn <<<dim3(32, 32), 256, 0, stream>>>(Q, K, Vt, AO);
    gemm_out   <<<dim3(32, 8),  256, 0, stream>>>(AO, wob, out);
}

// Round 4
// 214.678 us; speedup vs baseline: 1.4184x; 1.0683x over previous
//
#include <hip/hip_runtime.h>

typedef __attribute__((ext_vector_type(8))) __bf16 bf16x8;
typedef __attribute__((ext_vector_type(4))) float f32x4;
typedef __attribute__((ext_vector_type(8))) unsigned short u16x8;

#define MFMA(a, b, c) __builtin_amdgcn_mfma_f32_16x16x32_bf16((a), (b), (c), 0, 0, 0)
#define LOG2E 1.44269504088896340736f

__device__ __forceinline__ float b2f(unsigned short u) {
    union { unsigned int i; float f; } v; v.i = ((unsigned int)u) << 16; return v.f;
}
__device__ __forceinline__ unsigned short f2bf(float f) {
    union { float f; unsigned int i; } v; v.f = f;
    unsigned int u = v.i;
    return (unsigned short)((u + 0x7fffu + ((u >> 16) & 1u)) >> 16);
}

// async global->LDS, 16B/lane. HW dest = wave-uniform base + lane*16 (m104).
// Swizzling is done on the GLOBAL side so conflict-free LDS layouts coexist with it.
__device__ __forceinline__ void gl_lds16(const void* g, void* l) {
    __builtin_amdgcn_global_load_lds(
        (const __attribute__((address_space(1))) void*)g,
        (__attribute__((address_space(3))) void*)l,
        16, 0, 0);
}

// ---------------- fp32 -> bf16 conversion of all 5 inputs (one launch) ------------
__global__ __launch_bounds__(256) void cvt_all(const float* __restrict__ x,
                                               const float* __restrict__ wq,
                                               const float* __restrict__ wk,
                                               const float* __restrict__ wv,
                                               const float* __restrict__ wo,
                                               unsigned short* __restrict__ xb,
                                               unsigned short* __restrict__ wqb,
                                               unsigned short* __restrict__ wkb,
                                               unsigned short* __restrict__ wvb,
                                               unsigned short* __restrict__ wob) {
    int id = blockIdx.x * 256 + threadIdx.x;  // [0, 1M)
    const float* src; unsigned short* dst; size_t off;
    if (id < 524288)      { src = x;  dst = xb;  off = (size_t)id * 8; }
    else if (id < 655360) { src = wq; dst = wqb; off = (size_t)(id - 524288) * 8; }
    else if (id < 786432) { src = wk; dst = wkb; off = (size_t)(id - 655360) * 8; }
    else if (id < 917504) { src = wv; dst = wvb; off = (size_t)(id - 786432) * 8; }
    else                  { src = wo; dst = wob; off = (size_t)(id - 917504) * 8; }
    float4 a = *(const float4*)(src + off);
    float4 b = *(const float4*)(src + off + 4);
    u16x8 o;
    o[0] = f2bf(a.x); o[1] = f2bf(a.y); o[2] = f2bf(a.z); o[3] = f2bf(a.w);
    o[4] = f2bf(b.x); o[5] = f2bf(b.y); o[6] = f2bf(b.z); o[7] = f2bf(b.w);
    *(u16x8*)(dst + off) = o;
}

// ---------------- GEMM: C[MxN] = A[MxK]*B[NxK]^T, bf16 in, fp32 accum -------------
// 128x128 tile, BK=32. LDS chunk (r,cpos) holds source chunk cpos^((r>>1)&3)
// -> frag ds_read_b128 is 2-way (free) instead of 8-way.
template <typename OutT>
__device__ __forceinline__ void gemm128_bt(const unsigned short* __restrict__ A,
                                           const unsigned short* __restrict__ B,
                                           OutT* __restrict__ C,
                                           int m0, int n0,
                                           unsigned short* As, unsigned short* Bs) {
    const int tid = threadIdx.x;
    const int w = tid >> 6, lane = tid & 63;
    const int quad = lane >> 4, l15 = lane & 15;
    const int wm = w & 1, wn = w >> 1;

    f32x4 acc[4][4];
#pragma unroll
    for (int mt = 0; mt < 4; ++mt)
#pragma unroll
        for (int nt = 0; nt < 4; ++nt) acc[mt][nt] = f32x4{0.f, 0.f, 0.f, 0.f};

    for (int k0 = 0; k0 < 1024; k0 += 32) {
        __syncthreads();
#pragma unroll
        for (int i = 0; i < 2; ++i) {
            int L = (w * 2 + i) * 64 + lane;      // chunk index in tile
            int r = L >> 2;
            int c = (L & 3) ^ ((r >> 1) & 3);     // swizzled source chunk
            gl_lds16(A + (size_t)(m0 + r) * 1024 + k0 + c * 8, As + L * 8);
            gl_lds16(B + (size_t)(n0 + r) * 1024 + k0 + c * 8, Bs + L * 8);
        }
        __syncthreads();

        bf16x8 af[4], bfr[4];
#pragma unroll
        for (int mt = 0; mt < 4; ++mt) {
            int row = wm * 64 + mt * 16 + l15;
            af[mt] = *(const bf16x8*)(As + row * 32 + (quad ^ ((row >> 1) & 3)) * 8);
        }
#pragma unroll
        for (int nt = 0; nt < 4; ++nt) {
            int row = wn * 64 + nt * 16 + l15;
            bfr[nt] = *(const bf16x8*)(Bs + row * 32 + (quad ^ ((row >> 1) & 3)) * 8);
        }
#pragma unroll
        for (int mt = 0; mt < 4; ++mt)
#pragma unroll
            for (int nt = 0; nt < 4; ++nt)
                acc[mt][nt] = MFMA(af[mt], bfr[nt], acc[mt][nt]);
    }

#pragma unroll
    for (int mt = 0; mt < 4; ++mt) {
        int grow = m0 + wm * 64 + mt * 16 + quad * 4;
#pragma unroll
        for (int nt = 0; nt < 4; ++nt) {
            int gcol = n0 + wn * 64 + nt * 16 + l15;
#pragma unroll
            for (int r = 0; r < 4; ++r) {
                float val = acc[mt][nt][r];
                if constexpr (sizeof(OutT) == 2)
                    C[(size_t)(grow + r) * 1024 + gcol] = (OutT)f2bf(val);
                else
                    C[(size_t)(grow + r) * 1024 + gcol] = (OutT)val;
            }
        }
    }
}

__global__ __launch_bounds__(256) void gemm_qkv(const unsigned short* __restrict__ X,
                                                const unsigned short* __restrict__ Wq,
                                                const unsigned short* __restrict__ Wk,
                                                const unsigned short* __restrict__ Wv,
                                                unsigned short* __restrict__ Qo,
                                                unsigned short* __restrict__ Ko,
                                                unsigned short* __restrict__ Vo) {
    __shared__ unsigned short As[128 * 32];
    __shared__ unsigned short Bs[128 * 32];
    int m0 = blockIdx.x * 128;
    int sel = blockIdx.y >> 3;
    int n0 = (blockIdx.y & 7) * 128;
    const unsigned short* B = (sel == 0) ? Wq : ((sel == 1) ? Wk : Wv);
    unsigned short* C = (sel == 0) ? Qo : ((sel == 1) ? Ko : Vo);
    gemm128_bt<unsigned short>(X, B, C, m0, n0, As, Bs);
}

__global__ __launch_bounds__(256) void gemm_out(const unsigned short* __restrict__ A,
                                                const unsigned short* __restrict__ Wo,
                                                float* __restrict__ C) {
    __shared__ unsigned short As[128 * 32];
    __shared__ unsigned short Bs[128 * 32];
    gemm128_bt<float>(A, Wo, C, blockIdx.x * 128, blockIdx.y * 128, As, Bs);
}

// ---------------- RoPE in-place; Q gets 0.125*log2(e) folded in (M=0 softmax) -----
__global__ __launch_bounds__(256) void rope_qk(unsigned short* __restrict__ Q,
                                               unsigned short* __restrict__ K) {
    int id = blockIdx.x * 256 + threadIdx.x;   // 0 .. 2*4096*512-1
    int tsel = id >> 21;
    int rgt = id & 0x1FFFFF;
    int row = rgt >> 9;
    int p = rgt & 511;
    int pp = p & 31;
    int col = (p >> 5) * 64 + pp * 2;
    float pos = (float)(row & 2047);
    float inv_freq = exp2f(-0.41524101186092029f * (float)pp);
    float ang = pos * inv_freq;
    float sn, cs;
    sincosf(ang, &sn, &cs);
    unsigned short* buf = tsel ? K : Q;
    float scale = tsel ? 1.0f : (0.125f * LOG2E);
    size_t base = (size_t)row * 1024 + col;
    float xe = b2f(buf[base]), xo = b2f(buf[base + 1]);
    buf[base]     = f2bf((xe * cs - xo * sn) * scale);
    buf[base + 1] = f2bf((xe * sn + xo * cs) * scale);
}

// ---------------- V transpose: [b*2048+s][h*64+d] -> Vt[bh][d][s] ------------------
__global__ __launch_bounds__(256) void transpose_v(const unsigned short* __restrict__ V,
                                                   unsigned short* __restrict__ Vt) {
    int st = blockIdx.x, bh = blockIdx.y;
    int b = bh >> 4, h = bh & 15;
    __shared__ unsigned short t[64][72];
    int tid = threadIdx.x;
#pragma unroll
    for (int it = 0; it < 2; ++it) {
        int idx = it * 256 + tid;
        int sl = idx >> 3, dg = (idx & 7) * 8;
        u16x8 val = *(const u16x8*)(V + (size_t)(b * 2048 + st * 64 + sl) * 1024 + h * 64 + dg);
#pragma unroll
        for (int j = 0; j < 8; ++j) t[sl][dg + j] = val[j];
    }
    __syncthreads();
#pragma unroll
    for (int it = 0; it < 2; ++it) {
        int idx = it * 256 + tid;
        int dl = idx >> 3, sg = (idx & 7) * 8;
        u16x8 v;
#pragma unroll
        for (int j = 0; j < 8; ++j) v[j] = t[sg + j][dl];
        *(u16x8*)(Vt + (size_t)(bh * 64 + dl) * 2048 + st * 64 + sg) = v;
    }
}

// ---------------- Flash attention, causal, M=0, double-buffered K/V ----------------
// 1D grid 1024, XCD-swizzled: id = (bh&7) + 8*(qt' + 32*(bh>>3)) so all 32 q-tiles
// of one bh land on one XCD (K/V stream becomes L2-resident). stage(kb+1) is issued
// right after the barrier -> its latency overlaps compute on buf kb.
__global__ __launch_bounds__(256) void flash_attn(const unsigned short* __restrict__ Q,
                                                  const unsigned short* __restrict__ Kb,
                                                  const unsigned short* __restrict__ Vt,
                                                  unsigned short* __restrict__ O) {
    int id = blockIdx.x;
    int xcd = id & 7, rem = id >> 3;
    int qt = 31 - (rem & 31);          // largest tiles first within each XCD
    int bh = xcd + 8 * (rem >> 5);
    int b = bh >> 4, h = bh & 15;
    int tid = threadIdx.x, w = tid >> 6, lane = tid & 63;
    int quad = lane >> 4, l15 = lane & 15;
    int qrow0 = b * 2048 + qt * 64 + w * 16;
    int qpos0 = qt * 64 + w * 16;

    __shared__ unsigned short Ks[2][64 * 64];  // [key][d], chunk-swizzled
    __shared__ unsigned short Vs[2][64 * 64];  // [d][key], chunk-swizzled
    __shared__ unsigned short Ps[4][16 * 72];  // per-wave P scratch, stride 72

    bf16x8 qf0, qf1;
    {
        const unsigned short* qp = Q + (size_t)(qrow0 + l15) * 1024 + h * 64 + quad * 8;
        qf0 = *(const bf16x8*)qp;
        qf1 = *(const bf16x8*)(qp + 32);
    }

    // staging: chunk L=(w*2+i)*64+lane; row r=L>>3, lds col cpos=L&7 holds src cpos^(r&7)
    int L0 = w * 128 + lane;
    int L1 = L0 + 64;
    int r0 = L0 >> 3, c0s = (L0 & 7) ^ (r0 & 7);
    int r1 = L1 >> 3, c1s = (L1 & 7) ^ (r1 & 7);
    const unsigned short* Kg0 = Kb + (size_t)(b * 2048 + r0) * 1024 + h * 64 + c0s * 8;
    const unsigned short* Kg1 = Kb + (size_t)(b * 2048 + r1) * 1024 + h * 64 + c1s * 8;
    const unsigned short* Vg0 = Vt + (size_t)(bh * 64 + r0) * 2048 + c0s * 8;
    const unsigned short* Vg1 = Vt + (size_t)(bh * 64 + r1) * 2048 + c1s * 8;

    f32x4 accO[4];
#pragma unroll
    for (int nt = 0; nt < 4; ++nt) accO[nt] = f32x4{0.f, 0.f, 0.f, 0.f};
    float lsum[4] = {0.f, 0.f, 0.f, 0.f};

    int nkb = qt + 1;

    // prologue: stage block 0 into buf 0
    {
        gl_lds16(Kg0, Ks[0] + L0 * 8);
        gl_lds16(Kg1, Ks[0] + L1 * 8);
        gl_lds16(Vg0, Vs[0] + L0 * 8);
        gl_lds16(Vg1, Vs[0] + L1 * 8);
    }

    for (int kb = 0; kb < nkb; ++kb) {
        __syncthreads();  // drains this wave's stage(kb) loads, then barrier
        if (kb + 1 < nkb) {
            int bi = (kb + 1) & 1;
            size_t ko = (size_t)(kb + 1) * 64 * 1024;
            size_t vo = (size_t)(kb + 1) * 64;
            gl_lds16(Kg0 + ko, Ks[bi] + L0 * 8);
            gl_lds16(Kg1 + ko, Ks[bi] + L1 * 8);
            gl_lds16(Vg0 + vo, Vs[bi] + L0 * 8);
            gl_lds16(Vg1 + vo, Vs[bi] + L1 * 8);
        }
        const unsigned short* Kc = Ks[kb & 1];
        const unsigned short* Vc = Vs[kb & 1];

        if (kb * 64 <= qpos0 + 15) {   // wave-uniform skip of fully-masked blocks
            // ---- S' = (QK^T) * 0.125*log2e (folded into Q) ----
            f32x4 s[4];
#pragma unroll
            for (int nt = 0; nt < 4; ++nt) {
                int row = nt * 16 + l15;
                int cof = (quad ^ (row & 7)) * 8;
                bf16x8 kf0 = *(const bf16x8*)(Kc + row * 64 + cof);
                bf16x8 kf1 = *(const bf16x8*)(Kc + row * 64 + (cof ^ 32));
                f32x4 z = f32x4{0.f, 0.f, 0.f, 0.f};
                s[nt] = MFMA(qf0, kf0, z);
                s[nt] = MFMA(qf1, kf1, s[nt]);
            }
            // ---- P = exp2(s'), mask, accumulate denominator, store bf16 P ----
            unsigned short* Pw = Ps[w];
#pragma unroll
            for (int nt = 0; nt < 4; ++nt) {
                int kpos = kb * 64 + nt * 16 + l15;
#pragma unroll
                for (int r = 0; r < 4; ++r) {
                    int qpos = qpos0 + quad * 4 + r;
                    float e = exp2f(s[nt][r]);
                    e = (kpos > qpos) ? 0.f : e;
                    lsum[r] += e;
                    Pw[(quad * 4 + r) * 72 + nt * 16 + l15] = f2bf(e);
                }
            }
            __asm__ volatile("s_waitcnt lgkmcnt(0)" ::: "memory");  // wave-local LDS RAW
            bf16x8 pf0 = *(const bf16x8*)(Pw + l15 * 72 + quad * 8);
            bf16x8 pf1 = *(const bf16x8*)(Pw + l15 * 72 + 32 + quad * 8);
            // ---- O += P V ----
#pragma unroll
            for (int nt = 0; nt < 4; ++nt) {
                int row = nt * 16 + l15;
                int cof = (quad ^ (row & 7)) * 8;
                bf16x8 vf0 = *(const bf16x8*)(Vc + row * 64 + cof);
                bf16x8 vf1 = *(const bf16x8*)(Vc + row * 64 + (cof ^ 32));
                accO[nt] = MFMA(pf0, vf0, accO[nt]);
                accO[nt] = MFMA(pf1, vf1, accO[nt]);
            }
        }
    }
    // ---- epilogue: reduce denominator across the 16 lanes of each quad ----
#pragma unroll
    for (int off = 1; off < 16; off <<= 1)
#pragma unroll
        for (int r = 0; r < 4; ++r) lsum[r] += __shfl_xor(lsum[r], off);
    float inv[4];
#pragma unroll
    for (int r = 0; r < 4; ++r) inv[r] = 1.0f / lsum[r];
#pragma unroll
    for (int nt = 0; nt < 4; ++nt)
#pragma unroll
        for (int r = 0; r < 4; ++r)
            O[(size_t)(qrow0 + quad * 4 + r) * 1024 + h * 64 + nt * 16 + l15] =
                f2bf(accO[nt][r] * inv[r]);
}

extern "C" void kernel_launch(void* const* d_in, const int* in_sizes, int n_in,
                              void* d_out, int out_size, void* d_ws, size_t ws_size,
                              hipStream_t stream) {
    (void)in_sizes; (void)n_in; (void)out_size; (void)ws_size;
    const float* x  = (const float*)d_in[0];
    const float* wq = (const float*)d_in[1];
    const float* wk = (const float*)d_in[2];
    const float* wv = (const float*)d_in[3];
    const float* wo = (const float*)d_in[4];
    float* out = (float*)d_out;

    const size_t T = (size_t)4096 * 1024;
    const size_t W = (size_t)1024 * 1024;
    unsigned short* Q   = (unsigned short*)d_ws;
    unsigned short* K   = Q + T;
    unsigned short* Vt  = K + T;
    unsigned short* Vr  = Vt + T;
    unsigned short* AO  = Vr + T;
    unsigned short* xb  = AO + T;
    unsigned short* wqb = xb + T;
    unsigned short* wkb = wqb + W;
    unsigned short* wvb = wkb + W;
    unsigned short* wob = wvb + W;

    cvt_all    <<<dim3(4096),   256, 0, stream>>>(x, wq, wk, wv, wo, xb, wqb, wkb, wvb, wob);
    gemm_qkv   <<<dim3(32, 24), 256, 0, stream>>>(xb, wqb, wkb, wvb, Q, K, Vr);
    rope_qk    <<<dim3(16384),  256, 0, stream>>>(Q, K);
    transpose_v<<<dim3(32, 32), 256, 0, stream>>>(Vr, Vt);
    flash_attn <<<dim3(1024),   256, 0, stream>>>(Q, K, Vt, AO);
    gemm_out   <<<dim3(32, 8),  256, 0, stream>>>(AO, wob, out);
}

// Round 5
// 197.974 us; speedup vs baseline: 1.5381x; 1.0844x over previous
//
#include <hip/hip_runtime.h>

typedef __attribute__((ext_vector_type(8))) __bf16 bf16x8;
typedef __attribute__((ext_vector_type(8))) _Float16 f16x8;
typedef __attribute__((ext_vector_type(2))) _Float16 f16x2;
typedef __attribute__((ext_vector_type(4))) float f32x4;
typedef __attribute__((ext_vector_type(8))) unsigned short u16x8;

#define MFMA_BF16(a, b, c) __builtin_amdgcn_mfma_f32_16x16x32_bf16((a), (b), (c), 0, 0, 0)
#define MFMA_F16(a, b, c)  __builtin_amdgcn_mfma_f32_16x16x32_f16((a), (b), (c), 0, 0, 0)
#define LOG2E 1.44269504088896340736f

__device__ __forceinline__ float b2f(unsigned short u) {
    union { unsigned int i; float f; } v; v.i = ((unsigned int)u) << 16; return v.f;
}
__device__ __forceinline__ unsigned short f2bf(float f) {
    union { float f; unsigned int i; } v; v.f = f;
    unsigned int u = v.i;
    return (unsigned short)((u + 0x7fffu + ((u >> 16) & 1u)) >> 16);
}

// async global->LDS, 16B/lane. HW dest = wave-uniform base + lane*16 (m104).
// Swizzle is applied on the GLOBAL side so conflict-free LDS layouts coexist with it.
__device__ __forceinline__ void gl_lds16(const void* g, void* l) {
    __builtin_amdgcn_global_load_lds(
        (const __attribute__((address_space(1))) void*)g,
        (__attribute__((address_space(3))) void*)l,
        16, 0, 0);
}

// ---------------- fp32 -> bf16 conversion of all 5 inputs (one launch) ------------
__global__ __launch_bounds__(256) void cvt_all(const float* __restrict__ x,
                                               const float* __restrict__ wq,
                                               const float* __restrict__ wk,
                                               const float* __restrict__ wv,
                                               const float* __restrict__ wo,
                                               unsigned short* __restrict__ xb,
                                               unsigned short* __restrict__ wqb,
                                               unsigned short* __restrict__ wkb,
                                               unsigned short* __restrict__ wvb,
                                               unsigned short* __restrict__ wob) {
    int id = blockIdx.x * 256 + threadIdx.x;  // [0, 1M)
    const float* src; unsigned short* dst; size_t off;
    if (id < 524288)      { src = x;  dst = xb;  off = (size_t)id * 8; }
    else if (id < 655360) { src = wq; dst = wqb; off = (size_t)(id - 524288) * 8; }
    else if (id < 786432) { src = wk; dst = wkb; off = (size_t)(id - 655360) * 8; }
    else if (id < 917504) { src = wv; dst = wvb; off = (size_t)(id - 786432) * 8; }
    else                  { src = wo; dst = wob; off = (size_t)(id - 917504) * 8; }
    float4 a = *(const float4*)(src + off);
    float4 b = *(const float4*)(src + off + 4);
    u16x8 o;
    o[0] = f2bf(a.x); o[1] = f2bf(a.y); o[2] = f2bf(a.z); o[3] = f2bf(a.w);
    o[4] = f2bf(b.x); o[5] = f2bf(b.y); o[6] = f2bf(b.z); o[7] = f2bf(b.w);
    *(u16x8*)(dst + off) = o;
}

// ---------------- GEMM core: C[MxN] = A[MxK]*B[NxK]^T, bf16 in, fp32 accum --------
// 128x128 tile, BK=32, K=1024 fixed, A/B row stride 1024. LDS chunk (r,cpos) holds
// source chunk cpos^((r>>1)&3) -> frag ds_read_b128 is 2-way (free).
// MODE: 0 = bf16 out, 1 = f32 out, 2 = f16 out. ldc runtime.
template <int MODE>
__device__ __forceinline__ void gemm128_bt(const unsigned short* __restrict__ A,
                                           const unsigned short* __restrict__ B,
                                           void* __restrict__ Cv,
                                           int m0, int n0, int ldc,
                                           unsigned short* As, unsigned short* Bs) {
    const int tid = threadIdx.x;
    const int w = tid >> 6, lane = tid & 63;
    const int quad = lane >> 4, l15 = lane & 15;
    const int wm = w & 1, wn = w >> 1;

    f32x4 acc[4][4];
#pragma unroll
    for (int mt = 0; mt < 4; ++mt)
#pragma unroll
        for (int nt = 0; nt < 4; ++nt) acc[mt][nt] = f32x4{0.f, 0.f, 0.f, 0.f};

    for (int k0 = 0; k0 < 1024; k0 += 32) {
        __syncthreads();
#pragma unroll
        for (int i = 0; i < 2; ++i) {
            int L = (w * 2 + i) * 64 + lane;      // chunk index in tile
            int r = L >> 2;
            int c = (L & 3) ^ ((r >> 1) & 3);     // swizzled source chunk
            gl_lds16(A + (size_t)(m0 + r) * 1024 + k0 + c * 8, As + L * 8);
            gl_lds16(B + (size_t)(n0 + r) * 1024 + k0 + c * 8, Bs + L * 8);
        }
        __syncthreads();

        bf16x8 af[4], bfr[4];
#pragma unroll
        for (int mt = 0; mt < 4; ++mt) {
            int row = wm * 64 + mt * 16 + l15;
            af[mt] = *(const bf16x8*)(As + row * 32 + (quad ^ ((row >> 1) & 3)) * 8);
        }
#pragma unroll
        for (int nt = 0; nt < 4; ++nt) {
            int row = wn * 64 + nt * 16 + l15;
            bfr[nt] = *(const bf16x8*)(Bs + row * 32 + (quad ^ ((row >> 1) & 3)) * 8);
        }
#pragma unroll
        for (int mt = 0; mt < 4; ++mt)
#pragma unroll
            for (int nt = 0; nt < 4; ++nt)
                acc[mt][nt] = MFMA_BF16(af[mt], bfr[nt], acc[mt][nt]);
    }

#pragma unroll
    for (int mt = 0; mt < 4; ++mt) {
        int grow = m0 + wm * 64 + mt * 16 + quad * 4;
#pragma unroll
        for (int nt = 0; nt < 4; ++nt) {
            int gcol = n0 + wn * 64 + nt * 16 + l15;
#pragma unroll
            for (int r = 0; r < 4; ++r) {
                float val = acc[mt][nt][r];
                size_t idx = (size_t)(grow + r) * ldc + gcol;
                if constexpr (MODE == 0) {
                    ((unsigned short*)Cv)[idx] = f2bf(val);
                } else if constexpr (MODE == 1) {
                    ((float*)Cv)[idx] = val;
                } else {
                    _Float16 hv = (_Float16)val;
                    ((unsigned short*)Cv)[idx] = __builtin_bit_cast(unsigned short, hv);
                }
            }
        }
    }
}

// Q/K: C[token][ch] bf16 (ldc 1024). V: C = Wv * X^T = V^T[ch][token] f16 (ldc 4096),
// which is exactly the layout flash PV wants -> no transpose kernel.
__global__ __launch_bounds__(256) void gemm_qkv(const unsigned short* __restrict__ X,
                                                const unsigned short* __restrict__ Wq,
                                                const unsigned short* __restrict__ Wk,
                                                const unsigned short* __restrict__ Wv,
                                                unsigned short* __restrict__ Qo,
                                                unsigned short* __restrict__ Ko,
                                                unsigned short* __restrict__ Vt) {
    __shared__ unsigned short As[128 * 32];
    __shared__ unsigned short Bs[128 * 32];
    int y = blockIdx.y;
    if (y < 16) {
        int sel = y >> 3;
        int m0 = blockIdx.x * 128;         // tokens
        int n0 = (y & 7) * 128;            // channels
        const unsigned short* B = sel ? Wk : Wq;
        unsigned short* C = sel ? Ko : Qo;
        gemm128_bt<0>(X, B, C, m0, n0, 1024, As, Bs);
    } else {
        int m0 = (y & 7) * 128;            // channels
        int n0 = blockIdx.x * 128;         // tokens
        gemm128_bt<2>(Wv, X, Vt, m0, n0, 4096, As, Bs);
    }
}

__global__ __launch_bounds__(256) void gemm_out(const unsigned short* __restrict__ A,
                                                const unsigned short* __restrict__ Wo,
                                                float* __restrict__ C) {
    __shared__ unsigned short As[128 * 32];
    __shared__ unsigned short Bs[128 * 32];
    gemm128_bt<1>(A, Wo, C, blockIdx.x * 128, blockIdx.y * 128, 1024, As, Bs);
}

// ---------------- RoPE in-place; Q gets 0.125*log2(e) folded in (M=0 softmax) -----
__global__ __launch_bounds__(256) void rope_qk(unsigned short* __restrict__ Q,
                                               unsigned short* __restrict__ K) {
    int id = blockIdx.x * 256 + threadIdx.x;   // 0 .. 2*4096*512-1
    int tsel = id >> 21;
    int rgt = id & 0x1FFFFF;
    int row = rgt >> 9;
    int p = rgt & 511;
    int pp = p & 31;
    int col = (p >> 5) * 64 + pp * 2;
    float pos = (float)(row & 2047);
    float inv_freq = exp2f(-0.41524101186092029f * (float)pp);
    float ang = pos * inv_freq;
    float sn, cs;
    sincosf(ang, &sn, &cs);
    unsigned short* buf = tsel ? K : Q;
    float scale = tsel ? 1.0f : (0.125f * LOG2E);
    size_t base = (size_t)row * 1024 + col;
    float xe = b2f(buf[base]), xo = b2f(buf[base + 1]);
    buf[base]     = f2bf((xe * cs - xo * sn) * scale);
    buf[base + 1] = f2bf((xe * sn + xo * cs) * scale);
}

// ---------------- Flash attention, causal, M=0, double-buffered K/V ----------------
// grid 1024 XCD-swizzled (all q-tiles of a bh on one XCD -> K/V L2-resident).
// Mask exists only in the diagonal block (kb==qt). P,V in fp16 (cvt_pkrtz packing);
// row-sum of P via MFMA against an all-ones fragment (no VALU adds, no shuffles).
#define FLASH_BODY(KB, MASKED)                                                          \
    {                                                                                   \
        const int kb_ = (KB);                                                           \
        const unsigned short* Kc = Ks[kb_ & 1];                                         \
        const unsigned short* Vc = Vs[kb_ & 1];                                         \
        f32x4 s[4];                                                                     \
        _Pragma("unroll")                                                               \
        for (int nt = 0; nt < 4; ++nt) {                                                \
            int row = nt * 16 + l15;                                                    \
            int cof = (quad ^ (row & 7)) * 8;                                           \
            bf16x8 kf0 = *(const bf16x8*)(Kc + row * 64 + cof);                         \
            bf16x8 kf1 = *(const bf16x8*)(Kc + row * 64 + (cof ^ 32));                  \
            f32x4 z = f32x4{0.f, 0.f, 0.f, 0.f};                                        \
            s[nt] = MFMA_BF16(qf0, kf0, z);                                             \
            s[nt] = MFMA_BF16(qf1, kf1, s[nt]);                                         \
        }                                                                               \
        unsigned short* Pw = Ps[w];                                                     \
        _Pragma("unroll")                                                               \
        for (int nt = 0; nt < 4; ++nt) {                                                \
            float e[4];                                                                 \
            _Pragma("unroll")                                                           \
            for (int r = 0; r < 4; ++r) {                                               \
                float ev = exp2f(s[nt][r]);                                             \
                if (MASKED) {                                                           \
                    int kpos = kb_ * 64 + nt * 16 + l15;                                \
                    int qpos = qpos0 + quad * 4 + r;                                    \
                    ev = (kpos > qpos) ? 0.f : ev;                                      \
                }                                                                       \
                e[r] = ev;                                                              \
            }                                                                           \
            unsigned pk01 = __builtin_bit_cast(unsigned,                                \
                                __builtin_amdgcn_cvt_pkrtz(e[0], e[1]));                \
            unsigned pk23 = __builtin_bit_cast(unsigned,                                \
                                __builtin_amdgcn_cvt_pkrtz(e[2], e[3]));                \
            int col = nt * 16 + l15;                                                    \
            Pw[(quad * 4 + 0) * 72 + col] = (unsigned short)pk01;                       \
            Pw[(quad * 4 + 1) * 72 + col] = (unsigned short)(pk01 >> 16);               \
            Pw[(quad * 4 + 2) * 72 + col] = (unsigned short)pk23;                       \
            Pw[(quad * 4 + 3) * 72 + col] = (unsigned short)(pk23 >> 16);               \
        }                                                                               \
        __asm__ volatile("s_waitcnt lgkmcnt(0)" ::: "memory");                          \
        f16x8 pf0 = *(const f16x8*)(Pw + l15 * 72 + quad * 8);                          \
        f16x8 pf1 = *(const f16x8*)(Pw + l15 * 72 + 32 + quad * 8);                     \
        lacc = MFMA_F16(pf0, ones, lacc);                                               \
        lacc = MFMA_F16(pf1, ones, lacc);                                               \
        _Pragma("unroll")                                                               \
        for (int nt = 0; nt < 4; ++nt) {                                                \
            int row = nt * 16 + l15;                                                    \
            int cof = (quad ^ (row & 7)) * 8;                                           \
            f16x8 vf0 = *(const f16x8*)(Vc + row * 64 + cof);                           \
            f16x8 vf1 = *(const f16x8*)(Vc + row * 64 + (cof ^ 32));                    \
            accO[nt] = MFMA_F16(pf0, vf0, accO[nt]);                                    \
            accO[nt] = MFMA_F16(pf1, vf1, accO[nt]);                                    \
        }                                                                               \
    }

__global__ __launch_bounds__(256) void flash_attn(const unsigned short* __restrict__ Q,
                                                  const unsigned short* __restrict__ Kb,
                                                  const unsigned short* __restrict__ Vt,
                                                  unsigned short* __restrict__ O) {
    int id = blockIdx.x;
    int xcd = id & 7, rem = id >> 3;
    int qt = 31 - (rem & 31);          // largest tiles first within each XCD
    int bh = xcd + 8 * (rem >> 5);
    int b = bh >> 4, h = bh & 15;
    int tid = threadIdx.x, w = tid >> 6, lane = tid & 63;
    int quad = lane >> 4, l15 = lane & 15;
    int qrow0 = b * 2048 + qt * 64 + w * 16;
    int qpos0 = qt * 64 + w * 16;

    __shared__ unsigned short Ks[2][64 * 64];  // bf16 [key][d], chunk-swizzled
    __shared__ unsigned short Vs[2][64 * 64];  // f16  [d][key], chunk-swizzled
    __shared__ unsigned short Ps[4][16 * 72];  // f16 per-wave P scratch, stride 72

    bf16x8 qf0, qf1;
    {
        const unsigned short* qp = Q + (size_t)(qrow0 + l15) * 1024 + h * 64 + quad * 8;
        qf0 = *(const bf16x8*)qp;
        qf1 = *(const bf16x8*)(qp + 32);
    }
    f16x8 ones;
#pragma unroll
    for (int j = 0; j < 8; ++j) ones[j] = (_Float16)1.0f;

    // staging: chunk L=(w*2+i)*64+lane; row r=L>>3, lds col cpos=L&7 holds src cpos^(r&7)
    int L0 = w * 128 + lane;
    int L1 = L0 + 64;
    int r0 = L0 >> 3, c0s = (L0 & 7) ^ (r0 & 7);
    int r1 = L1 >> 3, c1s = (L1 & 7) ^ (r1 & 7);
    const unsigned short* Kg0 = Kb + (size_t)(b * 2048 + r0) * 1024 + h * 64 + c0s * 8;
    const unsigned short* Kg1 = Kb + (size_t)(b * 2048 + r1) * 1024 + h * 64 + c1s * 8;
    const unsigned short* Vg0 = Vt + (size_t)(h * 64 + r0) * 4096 + b * 2048 + c0s * 8;
    const unsigned short* Vg1 = Vt + (size_t)(h * 64 + r1) * 4096 + b * 2048 + c1s * 8;

    f32x4 accO[4];
#pragma unroll
    for (int nt = 0; nt < 4; ++nt) accO[nt] = f32x4{0.f, 0.f, 0.f, 0.f};
    f32x4 lacc = f32x4{0.f, 0.f, 0.f, 0.f};

    // prologue: stage block 0 into buf 0
    gl_lds16(Kg0, Ks[0] + L0 * 8);
    gl_lds16(Kg1, Ks[0] + L1 * 8);
    gl_lds16(Vg0, Vs[0] + L0 * 8);
    gl_lds16(Vg1, Vs[0] + L1 * 8);

    for (int kb = 0; kb < qt; ++kb) {      // all fully-unmasked blocks
        __syncthreads();                    // drains stage(kb), then barrier
        int bi = (kb + 1) & 1;
        size_t ko = (size_t)(kb + 1) * 64 * 1024;
        size_t vo = (size_t)(kb + 1) * 64;
        gl_lds16(Kg0 + ko, Ks[bi] + L0 * 8);
        gl_lds16(Kg1 + ko, Ks[bi] + L1 * 8);
        gl_lds16(Vg0 + vo, Vs[bi] + L0 * 8);
        gl_lds16(Vg1 + vo, Vs[bi] + L1 * 8);
        FLASH_BODY(kb, 0)
    }
    __syncthreads();
    FLASH_BODY(qt, 1)                       // diagonal block, masked

    // ---- epilogue: O / rowsum (lacc reg r = rowsum of q-row quad*4+r) ----
    float inv[4];
#pragma unroll
    for (int r = 0; r < 4; ++r) inv[r] = 1.0f / lacc[r];
#pragma unroll
    for (int nt = 0; nt < 4; ++nt)
#pragma unroll
        for (int r = 0; r < 4; ++r)
            O[(size_t)(qrow0 + quad * 4 + r) * 1024 + h * 64 + nt * 16 + l15] =
                f2bf(accO[nt][r] * inv[r]);
}

extern "C" void kernel_launch(void* const* d_in, const int* in_sizes, int n_in,
                              void* d_out, int out_size, void* d_ws, size_t ws_size,
                              hipStream_t stream) {
    (void)in_sizes; (void)n_in; (void)out_size; (void)ws_size;
    const float* x  = (const float*)d_in[0];
    const float* wq = (const float*)d_in[1];
    const float* wk = (const float*)d_in[2];
    const float* wv = (const float*)d_in[3];
    const float* wo = (const float*)d_in[4];
    float* out = (float*)d_out;

    const size_t T = (size_t)4096 * 1024;
    const size_t W = (size_t)1024 * 1024;
    unsigned short* Q   = (unsigned short*)d_ws;
    unsigned short* K   = Q + T;
    unsigned short* Vt  = K + T;      // f16 [ch][token], ldc 4096
    unsigned short* AO  = Vt + T;
    unsigned short* xb  = AO + T;
    unsigned short* wqb = xb + T;
    unsigned short* wkb = wqb + W;
    unsigned short* wvb = wkb + W;
    unsigned short* wob = wvb + W;

    cvt_all  <<<dim3(4096),   256, 0, stream>>>(x, wq, wk, wv, wo, xb, wqb, wkb, wvb, wob);
    gemm_qkv <<<dim3(32, 24), 256, 0, stream>>>(xb, wqb, wkb, wvb, Q, K, Vt);
    rope_qk  <<<dim3(16384),  256, 0, stream>>>(Q, K);
    flash_attn<<<dim3(1024),  256, 0, stream>>>(Q, K, Vt, AO);
    gemm_out <<<dim3(32, 8),  256, 0, stream>>>(AO, wob, out);
}